// Round 6
// baseline (247.496 us; speedup 1.0000x reference)
//
#include <hip/hip_runtime.h>

#define EPS 1e-4f

// Native clang vector types.
typedef float v2f __attribute__((ext_vector_type(2)));
typedef float v4f __attribute__((ext_vector_type(4)));

constexpr int B = 2048;
constexpr int D = 3706;           // even: pairs never straddle rows
constexpr int NE = B * D;         // 7,589,888 elements
constexpr int NP = NE / 2;        // 3,794,944 pairs
constexpr int BLK = 256;
constexpr int NTILES = NP / BLK;  // 14824 tiles of 256 pairs (exact)
constexpr int GRIDB = 2048;       // persistent: 8 blocks/CU x 256 CUs
constexpr int TBASE = NTILES / GRIDB;   // 7
constexpr int TREM  = NTILES % GRIDB;   // 488 blocks get one extra tile
constexpr int SROW  = 257;        // padded LDS row stride in float4s

// Per-element bucketize. Boundaries are computed in the reference's exact
// fp32 order: step_k = max(L_k,0) + EPS first, then sequential cumsum adds.
__device__ __forceinline__ void bucketize(float a, float mb, v4f L,
                                          float* __restrict__ r6, float& v) {
    const float s0 = fmaxf(L.x, 0.0f) + EPS;
    const float s1 = fmaxf(L.y, 0.0f) + EPS;
    const float s2 = fmaxf(L.z, 0.0f) + EPS;
    const float s3 = fmaxf(L.w, 0.0f) + EPS;
    const float b0 = mb;
    const float b1 = b0 + s0;
    const float b2 = b1 + s1;
    const float b3 = b2 + s2;
    const float b4 = b3 + s3;

    // b is strictly increasing (steps >= EPS > 0), so {k : a > b_k} is a prefix.
    const int cnt = (int)(a > b0) + (int)(a > b1) + (int)(a > b2)
                  + (int)(a > b3) + (int)(a > b4);
    // heaviside(0)=0: if a equals any boundary, every dist entry is 0.
    const bool eq = (a == b0) | (a == b1) | (a == b2) | (a == b3) | (a == b4);
    const float ok = eq ? 0.0f : 1.0f;

#pragma unroll
    for (int r = 0; r < 6; ++r) r6[r] = (r == cnt) ? ok : 0.0f;
    v = eq ? 0.0f : (float)cnt;
}

__global__ __launch_bounds__(256) void disc_kernel(
        const float* __restrict__ fake,
        const float* __restrict__ minb,
        const float* __restrict__ lens,
        float* __restrict__ out) {
    // Padded-transposed staging (12,336 B): write side address-linear
    // (conflict-free); read side spreads bank groups (~minimum aliasing).
    // 8 blocks/CU x 12.3 KB = 98.7 KB < 160 KB -> occupancy capped by the
    // 32-wave limit, not LDS.
    __shared__ v4f sd[3 * SROW];

    const int t = threadIdx.x;
    const int b = blockIdx.x;
    // Contiguous tile range per block: block b owns tiles [tstart, tstart+tc).
    // Its dist stores walk a sequential 84-96 KB window; its val stores walk
    // a sequential 14-16 KB window. Chip-wide: 2048 long sequential streams
    // (fill-style) instead of 14824 ephemeral 12 KB windows.
    const int tstart = b * TBASE + (b < TREM ? b : TREM);
    const int tcount = TBASE + (b < TREM ? 1 : 0);

    const int w    = t >> 6;
    const int lane = t & 63;
    float* valbase = out + (size_t)NE * 6;

    for (int it = 0; it < tcount; ++it) {
        const int tile = tstart + it;
        const int p = tile * BLK + t;                       // pair index
        const unsigned d0 = ((unsigned)p * 2u) % (unsigned)D;  // even column

        const v2f a  = reinterpret_cast<const v2f*>(fake)[p];
        const v2f mb = *reinterpret_cast<const v2f*>(minb + d0); // 8B aligned
        const v4f L0 = reinterpret_cast<const v4f*>(lens)[d0];
        const v4f L1 = reinterpret_cast<const v4f*>(lens)[d0 + 1];

        float r0[6], r1[6], v0, v1;
        bucketize(a.x, mb.x, L0, r0, v0);
        bucketize(a.y, mb.y, L1, r1, v1);

        // val: 8B/lane, consecutive lanes -> coalesced 512B/wave chunk.
        reinterpret_cast<v2f*>(valbase)[p] = (v2f){v0, v1};

        // Thread t's quarter c is logical float4 j = 3t + c -> sd[c*SROW+t].
        sd[0 * SROW + t] = (v4f){r0[0], r0[1], r0[2], r0[3]};
        sd[1 * SROW + t] = (v4f){r0[4], r0[5], r1[0], r1[1]};
        sd[2 * SROW + t] = (v4f){r1[2], r1[3], r1[4], r1[5]};

        __syncthreads();

        // Tile's dist region = 768 consecutive float4s. Wave w writes the
        // contiguous logical range [192w, 192w+192) as 3 back-to-back 1KB
        // stores. Logical j -> source thread j/3, quarter j%3.
        v4f* dp = reinterpret_cast<v4f*>(out) + (size_t)tile * (3 * BLK);
#pragma unroll
        for (int m = 0; m < 3; ++m) {
            const int j = w * 192 + m * 64 + lane;
            const int src = j / 3;             // div by const -> mulhi+shift
            const int k = j - src * 3;
            dp[j] = sd[k * SROW + src];
        }

        __syncthreads();   // protect sd reuse next iteration
    }
}

extern "C" void kernel_launch(void* const* d_in, const int* in_sizes, int n_in,
                              void* d_out, int out_size, void* d_ws, size_t ws_size,
                              hipStream_t stream) {
    const float* fake = (const float*)d_in[0];   // [B, D]
    const float* minb = (const float*)d_in[1];   // [D]
    const float* lens = (const float*)d_in[2];   // [D, 4]
    float* out = (float*)d_out;                  // dist [B,D,6] then val [B,D]

    disc_kernel<<<GRIDB, BLK, 0, stream>>>(fake, minb, lens, out);
}

// Round 7
// 238.149 us; speedup vs baseline: 1.0392x; 1.0392x over previous
//
#include <hip/hip_runtime.h>

#define EPS 1e-4f

constexpr int B = 2048;
constexpr int D = 3706;          // even -> column pairs never straddle rows
constexpr int NP = B * D / 2;    // 3,794,944 = 14824 * 256 exactly
constexpr int BLK = 256;

// Per-element bucketize. Boundaries are computed in the reference's exact
// fp32 order: step_k = max(L_k,0) + EPS first, then sequential cumsum adds.
__device__ __forceinline__ void bucketize(float a, float mb, float4 L,
                                          float* __restrict__ r6, float& v) {
    const float s0 = fmaxf(L.x, 0.0f) + EPS;
    const float s1 = fmaxf(L.y, 0.0f) + EPS;
    const float s2 = fmaxf(L.z, 0.0f) + EPS;
    const float s3 = fmaxf(L.w, 0.0f) + EPS;
    const float b0 = mb;
    const float b1 = b0 + s0;
    const float b2 = b1 + s1;
    const float b3 = b2 + s2;
    const float b4 = b3 + s3;

    // b is strictly increasing (steps >= EPS > 0), so {k : a > b_k} is a prefix.
    const int cnt = (int)(a > b0) + (int)(a > b1) + (int)(a > b2)
                  + (int)(a > b3) + (int)(a > b4);
    // heaviside(0)=0: if a equals any boundary, every dist entry is 0.
    const bool eq = (a == b0) | (a == b1) | (a == b2) | (a == b3) | (a == b4);
    const float ok = eq ? 0.0f : 1.0f;

#pragma unroll
    for (int r = 0; r < 6; ++r) r6[r] = (r == cnt) ? ok : 0.0f;
    v = eq ? 0.0f : (float)cnt;
}

__global__ __launch_bounds__(256) void disc_kernel(
        const float* __restrict__ fake,
        const float* __restrict__ minb,
        const float* __restrict__ lens,
        float* __restrict__ out) {
    // Staging for this block's dist tile: 512 elements * 6 floats = 3072 floats
    // = 768 float4 = 12 KB. Enables fully coalesced global stores.
    __shared__ float4 sd[3 * BLK];

    const int t = threadIdx.x;
    const int p = blockIdx.x * BLK + t;             // pair index (grid exact, p < NP)
    const int flat = p << 1;                        // even flat element index
    const int d0 = flat % D;                        // even column index

    const float2 a2 = reinterpret_cast<const float2*>(fake)[p];
    const float2 mb = *reinterpret_cast<const float2*>(minb + d0);
    const float4 L0 = reinterpret_cast<const float4*>(lens)[d0];
    const float4 L1 = reinterpret_cast<const float4*>(lens)[d0 + 1];

    float r0[6], r1[6], v0, v1;
    bucketize(a2.x, mb.x, L0, r0, v0);
    bucketize(a2.y, mb.y, L1, r1, v1);

    // Thread t's 12 dist floats land at block-local float offset t*12
    // (= float4 index t*3).
    sd[t * 3 + 0] = make_float4(r0[0], r0[1], r0[2], r0[3]);
    sd[t * 3 + 1] = make_float4(r0[4], r0[5], r1[0], r1[1]);
    sd[t * 3 + 2] = make_float4(r1[2], r1[3], r1[4], r1[5]);

    // val: already coalesced (8B/lane, consecutive). Issue before the barrier
    // so it overlaps the LDS round-trip.
    float* val = out + (size_t)B * D * 6;
    reinterpret_cast<float2*>(val)[p] = make_float2(v0, v1);

    __syncthreads();

    // Block's dist region = 3072 consecutive floats at out + blockIdx*3072.
    // Thread t writes float4 indices {t, t+256, t+512}: 16B/lane, consecutive
    // lanes -> consecutive addresses. Fully coalesced.
    float4* dp = reinterpret_cast<float4*>(out) + (size_t)blockIdx.x * (3 * BLK);
    dp[t]           = sd[t];
    dp[t + BLK]     = sd[t + BLK];
    dp[t + 2 * BLK] = sd[t + 2 * BLK];
}

extern "C" void kernel_launch(void* const* d_in, const int* in_sizes, int n_in,
                              void* d_out, int out_size, void* d_ws, size_t ws_size,
                              hipStream_t stream) {
    const float* fake = (const float*)d_in[0];   // [B, D]
    const float* minb = (const float*)d_in[1];   // [D]
    const float* lens = (const float*)d_in[2];   // [D, 4]
    float* out = (float*)d_out;                  // dist [B,D,6] then val [B,D]

    const int grid = NP / BLK;                   // 14824, exact
    disc_kernel<<<grid, BLK, 0, stream>>>(fake, minb, lens, out);
}